// Round 1
// 116.880 us; speedup vs baseline: 1.0186x; 1.0186x over previous
//
#include <hip/hip_runtime.h>

#define H 200
#define D 768
#define BATCH 4
#define S 512
#define M (BATCH*S)     // 2048
#define KP 224          // H padded to mult of 32 (MFMA K-step)
#define NP 208          // H padded to mult of 16 (hv N-dim)
#define NCAT 400        // head|tail concatenated output cols
#define NC4 (H*H/4)     // 10000 float4-columns of V
#define VT_BLOCKS 313   // ceil(10000 cols / 32) ; block = 32 cols x 8 o-octs
#define PROJ_BLOCKS 400 // 1600 proj tiles (64 m x 25 n) / 4 waves per block
#define PAD_BLOCKS 32
#define K2_BLOCKS (VT_BLOCKS + PROJ_BLOCKS + PAD_BLOCKS)   // 745
#define PREP_BLOCKS 512

typedef __attribute__((ext_vector_type(8))) short bf16x8;   // 8 bf16 (4 VGPRs)
typedef __attribute__((ext_vector_type(4))) float f32x4;
typedef unsigned short us;

__device__ inline us f2bf(float f) {            // round-to-nearest-even fp32->bf16
    union { float f; unsigned u; } v; v.f = f;
    return (us)((v.u + 0x7FFF + ((v.u >> 16) & 1)) >> 16);
}

// ---------------------------------------------------------------------------
// prep_lite: x->bf16 (float4 vectorized) and W transpose+concat -> bf16.
// Only what proj needs; V-reduction moved into projvt to overlap with MFMA.
// ---------------------------------------------------------------------------
__global__ __launch_bounds__(256) void prep_lite(
        const float* __restrict__ x,  const float* __restrict__ Wh,
        const float* __restrict__ Wt,
        us* __restrict__ xb, us* __restrict__ Wcb) {
    const int GTH = PREP_BLOCKS * 256;
    int gtid = blockIdx.x * 256 + threadIdx.x;
    // x -> bf16 (M*D/4 = 393216 float4s)
    {
        const float4* x4 = (const float4*)x;
        ushort4* xb4 = (ushort4*)xb;
        for (int t = gtid; t < M * D / 4; t += GTH) {
            float4 v = x4[t];
            ushort4 o; o.x = f2bf(v.x); o.y = f2bf(v.y); o.z = f2bf(v.z); o.w = f2bf(v.w);
            xb4[t] = o;
        }
    }
    // W transpose+concat -> bf16: Wcb[n*D+k] = W{h|t}[k][n]  (L2-resident rereads)
    for (int id = gtid; id < NCAT * D; id += GTH) {
        int n = id / D, k = id % D;
        float v = (n < H) ? Wh[k * H + n] : Wt[k * H + (n - H)];
        Wcb[id] = f2bf(v);
    }
}

// ---------------------------------------------------------------------------
// projvt: one kernel, three block roles (complementary-pipe overlap):
//   [0, VT_BLOCKS)            V = sum_o Wd[o]*U[o]  (HBM-bound, 32 MB U read)
//   [VT_BLOCKS, +PROJ_BLOCKS) proj: C[2048,400] = xb @ Wcb^T, relu+bias,
//                             split head|tail. 4 waves/block, 32x16 tile each
//                             (verified tile math from previous proj_mfma).
//   [.., +PAD_BLOCKS)         pad zeroing (read only by hv/scores, safe here)
// ---------------------------------------------------------------------------
__global__ __launch_bounds__(256) void projvt(
        const float* __restrict__ U,  const float* __restrict__ Wd,
        const us* __restrict__ xb,    const us* __restrict__ Wcb,
        const float* __restrict__ bh, const float* __restrict__ bt,
        us* __restrict__ VTb, us* __restrict__ headb, us* __restrict__ tailb,
        us* __restrict__ hvb) {
    int bid = blockIdx.x;
    if (bid < VT_BLOCKS) {
        __shared__ float4 red[8][32];            // [oct][col] 4 KB
        int cl = threadIdx.x & 31, q = threadIdx.x >> 5;   // col-lane, o-oct
        int c = bid * 32 + cl;                   // float4-column of V
        const float4* U4 = (const float4*)U;
        float4 acc = make_float4(0.f, 0.f, 0.f, 0.f);
        if (c < NC4) {
            int o0 = q * 25;
            #pragma unroll
            for (int o = o0; o < o0 + 25; ++o) { // 25 independent 16B loads
                float w = Wd[o];
                float4 u = U4[(size_t)o * NC4 + c];  // half-wave contiguous 512B
                acc.x += w * u.x; acc.y += w * u.y;
                acc.z += w * u.z; acc.w += w * u.w;
            }
        }
        red[q][cl] = acc;
        __syncthreads();
        if (q == 0 && c < NC4) {
            #pragma unroll
            for (int g = 1; g < 8; ++g) {
                float4 r = red[g][cl];
                acc.x += r.x; acc.y += r.y; acc.z += r.z; acc.w += r.w;
            }
            int i = c / (H / 4), j0 = (c % (H / 4)) * 4;  // V row i, cols j0..+3
            VTb[(j0 + 0) * KP + i] = f2bf(acc.x);         // VTb[n][k] = V[k][n]
            VTb[(j0 + 1) * KP + i] = f2bf(acc.y);
            VTb[(j0 + 2) * KP + i] = f2bf(acc.z);
            VTb[(j0 + 3) * KP + i] = f2bf(acc.w);
        }
        return;
    }
    bid -= VT_BLOCKS;
    if (bid < PROJ_BLOCKS) {
        int w = threadIdx.x >> 6, lane = threadIdx.x & 63;
        int t = bid * 4 + w;                     // tile id in [0,1600)
        int quad = lane >> 4, col = lane & 15;
        int m0 = (t & 63) * 32, n0 = (t >> 6) * 16;  // consecutive t share n0-group
        const bf16x8* A0 = (const bf16x8*)(xb + (m0 + col) * D + quad * 8);
        const bf16x8* A1 = (const bf16x8*)(xb + (m0 + 16 + col) * D + quad * 8);
        const bf16x8* Bp = (const bf16x8*)(Wcb + (n0 + col) * D + quad * 8);
        f32x4 acc0 = {0.f,0.f,0.f,0.f}, acc1 = {0.f,0.f,0.f,0.f};
        #pragma unroll 4
        for (int kk = 0; kk < D / 32; ++kk) {
            bf16x8 a0 = A0[kk * 4];
            bf16x8 a1 = A1[kk * 4];
            bf16x8 b  = Bp[kk * 4];
            acc0 = __builtin_amdgcn_mfma_f32_16x16x32_bf16(a0, b, acc0, 0, 0, 0);
            acc1 = __builtin_amdgcn_mfma_f32_16x16x32_bf16(a1, b, acc1, 0, 0, 0);
        }
        int n = n0 + col;
        bool ish = (n < H);
        float bias = ish ? bh[n] : bt[n - H];
        us* dst = ish ? headb : tailb;
        int nn = ish ? n : n - H;
        #pragma unroll
        for (int r = 0; r < 4; ++r) {
            int ma = m0 + quad * 4 + r;
            dst[ma * KP + nn]        = f2bf(fmaxf(acc0[r] + bias, 0.f));
            dst[(ma + 16) * KP + nn] = f2bf(fmaxf(acc1[r] + bias, 0.f));
        }
        return;
    }
    bid -= PROJ_BLOCKS;
    const int GTH = PAD_BLOCKS * 256;
    int gtid = bid * 256 + threadIdx.x;
    // pad zeroing (ws poisoned 0xAA every call); all regions disjoint from
    // what VT/proj blocks write, so concurrent execution is race-free.
    for (int id = gtid; id < M * (KP - H); id += GTH) {
        int r = id / (KP - H), c = H + id % (KP - H);
        headb[r * KP + c] = 0; tailb[r * KP + c] = 0;
    }
    for (int id = gtid; id < M * (KP - NP); id += GTH) {
        int r = id / (KP - NP), c = NP + id % (KP - NP);
        hvb[r * KP + c] = 0;
    }
    for (int id = gtid; id < H * (KP - H); id += GTH) {      // n<H, k in [H,KP)
        int n = id / (KP - H), k = H + id % (KP - H);
        VTb[n * KP + k] = 0;
    }
    for (int id = gtid; id < (NP - H) * KP; id += GTH) {     // n in [H,NP), all k
        int n = H + id / KP, k = id % KP;
        VTb[n * KP + k] = 0;
    }
}

// ---------------------------------------------------------------------------
// hv[2048,208] = headb[2048,224] @ VTb[208,224]^T
// ---------------------------------------------------------------------------
__global__ __launch_bounds__(64) void hv_mfma(
        const us* __restrict__ headb, const us* __restrict__ VTb,
        us* __restrict__ hvb) {
    int lane = threadIdx.x, quad = lane >> 4, col = lane & 15;
    int m0 = blockIdx.x * 32, n0 = blockIdx.y * 16;
    const bf16x8* A0 = (const bf16x8*)(headb + (m0 + col) * KP + quad * 8);
    const bf16x8* A1 = (const bf16x8*)(headb + (m0 + 16 + col) * KP + quad * 8);
    const bf16x8* Bp = (const bf16x8*)(VTb + (n0 + col) * KP + quad * 8);
    f32x4 acc0 = {0.f,0.f,0.f,0.f}, acc1 = {0.f,0.f,0.f,0.f};
    #pragma unroll
    for (int kk = 0; kk < KP / 32; ++kk) {
        bf16x8 a0 = A0[kk * 4];
        bf16x8 a1 = A1[kk * 4];
        bf16x8 b  = Bp[kk * 4];
        acc0 = __builtin_amdgcn_mfma_f32_16x16x32_bf16(a0, b, acc0, 0, 0, 0);
        acc1 = __builtin_amdgcn_mfma_f32_16x16x32_bf16(a1, b, acc1, 0, 0, 0);
    }
    int n = n0 + col;
    #pragma unroll
    for (int r = 0; r < 4; ++r) {
        int ma = m0 + quad * 4 + r;
        hvb[ma * KP + n]        = f2bf(acc0[r]);
        hvb[(ma + 16) * KP + n] = f2bf(acc1[r]);
    }
}

// ---------------------------------------------------------------------------
// scores[b,x,y] = (hv[b,x,:].tail[b,y,:] + b_down)/sqrt(200); 32x32 per wave
// ---------------------------------------------------------------------------
__global__ __launch_bounds__(64) void scores_mfma(
        const us* __restrict__ hvb, const us* __restrict__ tailb,
        const float* __restrict__ bd, float* __restrict__ out) {
    int lane = threadIdx.x, quad = lane >> 4, col = lane & 15;
    int b = blockIdx.z;
    int m0 = blockIdx.x * 32, n0 = blockIdx.y * 32;
    const us* A  = hvb   + (size_t)b * S * KP;
    const us* Bm = tailb + (size_t)b * S * KP;
    const bf16x8* A0 = (const bf16x8*)(A  + (m0 + col) * KP + quad * 8);
    const bf16x8* A1 = (const bf16x8*)(A  + (m0 + 16 + col) * KP + quad * 8);
    const bf16x8* B0 = (const bf16x8*)(Bm + (n0 + col) * KP + quad * 8);
    const bf16x8* B1 = (const bf16x8*)(Bm + (n0 + 16 + col) * KP + quad * 8);
    f32x4 a00 = {0.f,0.f,0.f,0.f}, a01 = {0.f,0.f,0.f,0.f};
    f32x4 a10 = {0.f,0.f,0.f,0.f}, a11 = {0.f,0.f,0.f,0.f};
    #pragma unroll
    for (int kk = 0; kk < KP / 32; ++kk) {
        bf16x8 a0 = A0[kk * 4];
        bf16x8 a1 = A1[kk * 4];
        bf16x8 b0 = B0[kk * 4];
        bf16x8 b1 = B1[kk * 4];
        a00 = __builtin_amdgcn_mfma_f32_16x16x32_bf16(a0, b0, a00, 0, 0, 0);
        a01 = __builtin_amdgcn_mfma_f32_16x16x32_bf16(a0, b1, a01, 0, 0, 0);
        a10 = __builtin_amdgcn_mfma_f32_16x16x32_bf16(a1, b0, a10, 0, 0, 0);
        a11 = __builtin_amdgcn_mfma_f32_16x16x32_bf16(a1, b1, a11, 0, 0, 0);
    }
    float bias = bd[0];
    const float scale = 0.07071067811865475f;   // 1/sqrt(200)
    float* outb = out + (size_t)b * S * S;
    #pragma unroll
    for (int r = 0; r < 4; ++r) {
        int ma = m0 + quad * 4 + r, mb = ma + 16;
        outb[ma * S + n0 + col]      = (a00[r] + bias) * scale;
        outb[ma * S + n0 + 16 + col] = (a01[r] + bias) * scale;
        outb[mb * S + n0 + col]      = (a10[r] + bias) * scale;
        outb[mb * S + n0 + 16 + col] = (a11[r] + bias) * scale;
    }
}

extern "C" void kernel_launch(void* const* d_in, const int* in_sizes, int n_in,
                              void* d_out, int out_size, void* d_ws, size_t ws_size,
                              hipStream_t stream) {
    const float* x  = (const float*)d_in[0];
    const float* Wh = (const float*)d_in[1];
    const float* bh = (const float*)d_in[2];
    const float* Wt = (const float*)d_in[3];
    const float* bt = (const float*)d_in[4];
    const float* U  = (const float*)d_in[5];
    const float* Wd = (const float*)d_in[6];
    const float* bd = (const float*)d_in[7];
    float* out = (float*)d_out;

    // ws layout (bf16): xb | Wcb | VTb | hvb | headb | tailb  (~6.6 MB)
    us* xb    = (us*)d_ws;
    us* Wcb   = xb    + (size_t)M * D;
    us* VTb   = Wcb   + (size_t)NCAT * D;
    us* hvb   = VTb   + (size_t)NP * KP;
    us* headb = hvb   + (size_t)M * KP;
    us* tailb = headb + (size_t)M * KP;

    prep_lite<<<PREP_BLOCKS, 256, 0, stream>>>(x, Wh, Wt, xb, Wcb);
    projvt<<<K2_BLOCKS, 256, 0, stream>>>(U, Wd, xb, Wcb, bh, bt,
                                          VTb, headb, tailb, hvb);
    hv_mfma<<<dim3(M / 32, NP / 16), 64, 0, stream>>>(headb, VTb, hvb);
    scores_mfma<<<dim3(S / 32, S / 32, BATCH), 64, 0, stream>>>(hvb, tailb, bd, out);
}